// Round 13
// baseline (260.880 us; speedup 1.0000x reference)
//
#include <hip/hip_runtime.h>
#include <stdint.h>

#define IN_DIM 256
#define HID 128
#define BKT_BITS 6
#define BKT_SZ 64
#define MAXBKT 2048
#define NB_BLK 256   // partitions for contention-free scatter

typedef __attribute__((ext_vector_type(8))) short short8v;   // 8 bf16 (4 VGPRs)
typedef __attribute__((ext_vector_type(4))) float f32x4;     // MFMA acc
typedef __attribute__((ext_vector_type(2))) float f32x2;     // pk_add pair

// ---------------- bf16 helpers ----------------------------------------------
__device__ __forceinline__ unsigned short f2bf(float f) {
    unsigned u = __float_as_uint(f);
    unsigned rnd = 0x7FFFu + ((u >> 16) & 1u);
    return (unsigned short)((u + rnd) >> 16);
}
__device__ __forceinline__ float bflo(unsigned v) { return __uint_as_float(v << 16); }
__device__ __forceinline__ float bfhi(unsigned v) { return __uint_as_float(v & 0xFFFF0000u); }

// packed dual-f32 accumulate: acc.x += lo(v), acc.y += hi(v)
__device__ __forceinline__ void pkacc(f32x2& acc, unsigned v) {
    f32x2 t;
    t.x = __uint_as_float(v << 16);
    t.y = __uint_as_float(v & 0xFFFF0000u);
    asm("v_pk_add_f32 %0, %0, %1" : "+v"(acc) : "v"(t));
}

// ---------------- threefry2x32 dropout (JAX partitionable path) -------------
__device__ __forceinline__ unsigned rotl32(unsigned x, int r) {
    return (x << r) | (x >> (32 - r));
}
__device__ __forceinline__ float dropout_scale(unsigned idx) {
    const unsigned ks0 = 0u, ks1 = 42u, ks2 = 0x1BD11BF0u;
    unsigned x0 = 0u + ks0;
    unsigned x1 = idx + ks1;
#define TF_ROUND(r) { x0 += x1; x1 = rotl32(x1, r); x1 ^= x0; }
    TF_ROUND(13) TF_ROUND(15) TF_ROUND(26) TF_ROUND(6)
    x0 += ks1; x1 += ks2 + 1u;
    TF_ROUND(17) TF_ROUND(29) TF_ROUND(16) TF_ROUND(24)
    x0 += ks2; x1 += ks0 + 2u;
    TF_ROUND(13) TF_ROUND(15) TF_ROUND(26) TF_ROUND(6)
    x0 += ks0; x1 += ks1 + 3u;
    TF_ROUND(17) TF_ROUND(29) TF_ROUND(16) TF_ROUND(24)
    x0 += ks1; x1 += ks2 + 4u;
    TF_ROUND(13) TF_ROUND(15) TF_ROUND(26) TF_ROUND(6)
    x0 += ks2; x1 += ks0 + 5u;
#undef TF_ROUND
    unsigned bits = x0 ^ x1;
    float u = __uint_as_float(0x3F800000u | (bits >> 9)) - 1.0f;
    return (u < 0.9f) ? (1.0f / 0.9f) : 0.0f;
}

// ---------------- fused setup: part_count + weight cvt + zero row -----------
// blocks [0, NB_BLK): per-partition LDS histogram of dst buckets
// blocks [NB_BLK, ...): convert W1,W2 to bf16 and zero hA's padding row
__global__ __launch_bounds__(256) void setup(const int* __restrict__ dst,
                                             int* __restrict__ counts,
                                             int E, int nbkt, int per,
                                             const float* __restrict__ W1,
                                             unsigned short* __restrict__ Wb1, int na,
                                             const float* __restrict__ W2,
                                             unsigned short* __restrict__ Wb2, int nb,
                                             unsigned short* __restrict__ zrow) {
    if (blockIdx.x < NB_BLK) {
        __shared__ int lh[MAXBKT];
        for (int i = threadIdx.x; i < nbkt; i += 256) lh[i] = 0;
        __syncthreads();
        int blk = blockIdx.x;
        int beg = blk * per, end = min(E, beg + per);
        for (int i = beg + threadIdx.x; i < end; i += 256)
            atomicAdd(&lh[dst[i] >> BKT_BITS], 1);
        __syncthreads();
        for (int b = threadIdx.x; b < nbkt; b += 256)
            counts[b * NB_BLK + blk] = lh[b];
    } else {
        int i = (blockIdx.x - NB_BLK) * 256 + threadIdx.x;
        if (i < na) Wb1[i] = f2bf(W1[i]);
        else if (i < na + nb) Wb2[i - na] = f2bf(W2[i - na]);
        else if (i < na + nb + HID) zrow[i - na - nb] = 0;
    }
}

__global__ __launch_bounds__(256) void scan2_local(const int* __restrict__ in,
                                                   int* __restrict__ out,
                                                   int* __restrict__ bsum, int M) {
    __shared__ int lds[256];
    int t = threadIdx.x;
    int base = blockIdx.x * 2048 + t * 8;
    int x[8], v[8];
    if (base + 7 < M) {
        int4 a = *(const int4*)(in + base);
        int4 b = *(const int4*)(in + base + 4);
        x[0] = a.x; x[1] = a.y; x[2] = a.z; x[3] = a.w;
        x[4] = b.x; x[5] = b.y; x[6] = b.z; x[7] = b.w;
    } else {
        for (int j = 0; j < 8; ++j) x[j] = (base + j < M) ? in[base + j] : 0;
    }
    int s = 0;
    for (int j = 0; j < 8; ++j) { v[j] = s; s += x[j]; }
    lds[t] = s;
    __syncthreads();
    for (int d = 1; d < 256; d <<= 1) {
        int val = lds[t];
        int add = (t >= d) ? lds[t - d] : 0;
        __syncthreads();
        lds[t] = val + add;
        __syncthreads();
    }
    int excl = lds[t] - s;
    for (int j = 0; j < 8; ++j)
        if (base + j < M) out[base + j] = excl + v[j];
    if (t == 255) bsum[blockIdx.x] = lds[255];
}
__global__ __launch_bounds__(256) void scan2_bsums(int* __restrict__ bsum, int nb) {
    __shared__ int lds[256];
    int t = threadIdx.x;
    int orig = (t < nb) ? bsum[t] : 0;
    lds[t] = orig;
    __syncthreads();
    for (int d = 1; d < 256; d <<= 1) {
        int val = lds[t];
        int add = (t >= d) ? lds[t - d] : 0;
        __syncthreads();
        lds[t] = val + add;
        __syncthreads();
    }
    if (t < nb) bsum[t] = lds[t] - orig;
}
// adds scanned block sums AND extracts bucket bases (fused extract_bbase)
__global__ void scan2_add(int* __restrict__ out, const int* __restrict__ bsum,
                          int* __restrict__ bbase, int M, int nbkt, int E) {
    int i = blockIdx.x * blockDim.x + threadIdx.x;
    if (i < M) {
        int v = out[i] + bsum[i >> 11];
        out[i] = v;
        if ((i & (NB_BLK - 1)) == 0) bbase[i / NB_BLK] = v;
    }
    if (i == 0) bbase[nbkt] = E;
}

__global__ __launch_bounds__(256) void part_scatter(const int* __restrict__ src,
                                                    const int* __restrict__ dst,
                                                    const int* __restrict__ cbase,
                                                    unsigned* __restrict__ packed,
                                                    int E, int nbkt, int per) {
    __shared__ int cur[MAXBKT];
    int blk = blockIdx.x;
    for (int b = threadIdx.x; b < nbkt; b += 256)
        cur[b] = cbase[b * NB_BLK + blk];
    __syncthreads();
    int beg = blk * per, end = min(E, beg + per);
    for (int i = beg + threadIdx.x; i < end; i += 256) {
        int d = dst[i];
        int pos = atomicAdd(&cur[d >> BKT_BITS], 1);
        packed[pos] = ((unsigned)src[i] << BKT_BITS) | (unsigned)(d & (BKT_SZ - 1));
    }
}

// ssrc stores BYTE offsets (src << 8) for the 256-byte h rows.
// per-node offsets via single-wave shfl scan (2 barriers total).
__global__ __launch_bounds__(256) void bucket_finalize(const unsigned* __restrict__ packed,
                                                       const int* __restrict__ bbase,
                                                       int* __restrict__ ssrc,
                                                       int* __restrict__ offs,
                                                       float* __restrict__ dinv, int N) {
    __shared__ int hist[BKT_SZ];
    __shared__ int cur[BKT_SZ];
    int b = blockIdx.x;
    int t = threadIdx.x;
    int beg = bbase[b], end = bbase[b + 1];
    if (t < BKT_SZ) hist[t] = 0;
    __syncthreads();
    for (int i = beg + t; i < end; i += 256)
        atomicAdd(&hist[packed[i] & (BKT_SZ - 1)], 1);
    __syncthreads();
    if (t < BKT_SZ) {
        int v = hist[t];
        int x = v;
#pragma unroll
        for (int d = 1; d < 64; d <<= 1) {
            int y = __shfl_up(x, d, 64);
            if (t >= d) x += y;
        }
        int excl = x - v;                 // exclusive prefix within bucket
        int node = b * BKT_SZ + t;
        if (node < N) {
            offs[node] = beg + excl;
            dinv[node] = rsqrtf((float)(v + 1));
        }
        cur[t] = excl;
    }
    __syncthreads();
    for (int i = beg + t; i < end; i += 256) {
        unsigned p = packed[i];
        int dl = (int)(p & (BKT_SZ - 1));
        int pos = atomicAdd(&cur[dl], 1);
        ssrc[beg + pos] = (int)((p >> BKT_BITS) << 8);   // byte offset
    }
}

// ---------------- bf16 MFMA GEMM: C[Mx128] = diag(scale) * A[MxK] @ W^T -----
template <int K, int A_BF16>
__global__ __launch_bounds__(256) void gemm_mfma(const void* __restrict__ Ap,
                                                 const unsigned short* __restrict__ Wb,
                                                 const float* __restrict__ scale,
                                                 unsigned short* __restrict__ C,
                                                 int M) {
    constexpr int NKB = K / 32;
    constexpr int APAD = K + 8;
    __shared__ unsigned short Alds[64 * APAD];
    const int t = threadIdx.x;
    const int bm = blockIdx.x * 64;
    const int w = t >> 6, l = t & 63;
    const int lr = l & 15, lk = l >> 4;

    short8v bfrag[2][NKB];
#pragma unroll
    for (int cbi = 0; cbi < 2; ++cbi) {
        int col = (w * 2 + cbi) * 16 + lr;
#pragma unroll
        for (int kb = 0; kb < NKB; ++kb)
            bfrag[cbi][kb] = *(const short8v*)(Wb + (size_t)col * K + kb * 32 + lk * 8);
    }

    if constexpr (A_BF16) {
        constexpr int STEPS = 64 * K / (256 * 8);
        const unsigned short* Abase = (const unsigned short*)Ap;
#pragma unroll
        for (int i = 0; i < STEPS; ++i) {
            int flat = (i * 256 + t) * 8;
            int row = flat / K;
            int o = flat % K;
            short8v v = {};
            if (bm + row < M)
                v = *(const short8v*)(Abase + (size_t)(bm + row) * K + o);
            *(short8v*)(&Alds[row * APAD + o]) = v;
        }
    } else {
        constexpr int STEPS = 64 * K / (256 * 8);
        const float* Abase = (const float*)Ap;
#pragma unroll
        for (int i = 0; i < STEPS; ++i) {
            int flat = (i * 256 + t) * 8;
            int row = flat / K;
            int o = flat % K;
            short8v u = {};
            if (bm + row < M) {
                const float* p = Abase + (size_t)(bm + row) * K + o;
                float4 f0 = *(const float4*)(p);
                float4 f1 = *(const float4*)(p + 4);
                u[0] = (short)f2bf(f0.x); u[1] = (short)f2bf(f0.y);
                u[2] = (short)f2bf(f0.z); u[3] = (short)f2bf(f0.w);
                u[4] = (short)f2bf(f1.x); u[5] = (short)f2bf(f1.y);
                u[6] = (short)f2bf(f1.z); u[7] = (short)f2bf(f1.w);
            }
            *(short8v*)(&Alds[row * APAD + o]) = u;
        }
    }
    __syncthreads();

#pragma unroll
    for (int m = 0; m < 4; ++m) {
        short8v afr[NKB];
#pragma unroll
        for (int kb = 0; kb < NKB; ++kb)
            afr[kb] = *(const short8v*)(&Alds[(m * 16 + lr) * APAD + kb * 32 + lk * 8]);
        f32x4 acc[2] = {};
#pragma unroll
        for (int kb = 0; kb < NKB; ++kb) {
            acc[0] = __builtin_amdgcn_mfma_f32_16x16x32_bf16(afr[kb], bfrag[0][kb], acc[0], 0, 0, 0);
            acc[1] = __builtin_amdgcn_mfma_f32_16x16x32_bf16(afr[kb], bfrag[1][kb], acc[1], 0, 0, 0);
        }
        int r0 = bm + m * 16 + lk * 4;
        float scv[4];
#pragma unroll
        for (int j = 0; j < 4; ++j)
            scv[j] = (r0 + j < M) ? scale[r0 + j] : 0.f;
#pragma unroll
        for (int cbi = 0; cbi < 2; ++cbi) {
            int col = (w * 2 + cbi) * 16 + lr;
#pragma unroll
            for (int j = 0; j < 4; ++j) {
                if (r0 + j < M)
                    C[(size_t)(r0 + j) * 128 + col] = f2bf(acc[cbi][j] * scv[j]);
            }
        }
    }
}

// ---------------- CSR gather aggregation: 1 node per 64-thr block -----------
// h rows pre-scaled (h' = dinv*h); row N all-zero; ssrc holds BYTE offsets.
// 16 lanes per edge; 16 edges per iteration; offset loads software-pipelined.
// MODE 1: out(bf16) = dropout(relu(dn*sum + b));  MODE 2: out(fp32) = dn*sum + b
template <int MODE>
__global__ __launch_bounds__(64) void aggregate_csr(const unsigned* __restrict__ h,
                                                    const int* __restrict__ soff,
                                                    const int* __restrict__ ssrc,
                                                    const float* __restrict__ dinv,
                                                    const float* __restrict__ bias,
                                                    void* __restrict__ outp,
                                                    int N, int E) {
    int n = blockIdx.x;
    const int lane = threadIdx.x;
    const int g = lane >> 4;      // edge group 0..3
    const int f0 = lane & 15;     // 16B chunk within the 256B row
    int start = soff[n];
    int end = (n + 1 < N) ? soff[n + 1] : E;
    float dn = dinv[n];
    const char* __restrict__ hb = (const char*)h;
    const int zoff = N << 8;      // zero row byte offset
    const int coff = f0 * 16;     // chunk byte offset within row

    f32x2 A0 = {0.f, 0.f}, A1 = {0.f, 0.f}, A2 = {0.f, 0.f}, A3 = {0.f, 0.f};

    int i = start;
    int o0 = zoff, o1 = zoff, o2 = zoff, o3 = zoff;
    {
        int i0 = i + g, i1 = i0 + 4, i2 = i0 + 8, i3 = i0 + 12;
        if (i0 < end) o0 = ssrc[i0];
        if (i1 < end) o1 = ssrc[i1];
        if (i2 < end) o2 = ssrc[i2];
        if (i3 < end) o3 = ssrc[i3];
    }
    for (; i < end; i += 16) {
        uint4 v0 = *(const uint4*)(hb + (size_t)o0 + coff);
        uint4 v1 = *(const uint4*)(hb + (size_t)o1 + coff);
        uint4 v2 = *(const uint4*)(hb + (size_t)o2 + coff);
        uint4 v3 = *(const uint4*)(hb + (size_t)o3 + coff);
        int ni = i + 16;
        int i0 = ni + g, i1 = i0 + 4, i2 = i0 + 8, i3 = i0 + 12;
        o0 = (i0 < end) ? ssrc[i0] : zoff;
        o1 = (i1 < end) ? ssrc[i1] : zoff;
        o2 = (i2 < end) ? ssrc[i2] : zoff;
        o3 = (i3 < end) ? ssrc[i3] : zoff;
        pkacc(A0, v0.x); pkacc(A1, v0.y); pkacc(A2, v0.z); pkacc(A3, v0.w);
        pkacc(A0, v1.x); pkacc(A1, v1.y); pkacc(A2, v1.z); pkacc(A3, v1.w);
        pkacc(A0, v2.x); pkacc(A1, v2.y); pkacc(A2, v2.z); pkacc(A3, v2.w);
        pkacc(A0, v3.x); pkacc(A1, v3.y); pkacc(A2, v3.z); pkacc(A3, v3.w);
    }

    A0.x += __shfl_xor(A0.x, 16, 64); A0.x += __shfl_xor(A0.x, 32, 64);
    A0.y += __shfl_xor(A0.y, 16, 64); A0.y += __shfl_xor(A0.y, 32, 64);
    A1.x += __shfl_xor(A1.x, 16, 64); A1.x += __shfl_xor(A1.x, 32, 64);
    A1.y += __shfl_xor(A1.y, 16, 64); A1.y += __shfl_xor(A1.y, 32, 64);
    A2.x += __shfl_xor(A2.x, 16, 64); A2.x += __shfl_xor(A2.x, 32, 64);
    A2.y += __shfl_xor(A2.y, 16, 64); A2.y += __shfl_xor(A2.y, 32, 64);
    A3.x += __shfl_xor(A3.x, 16, 64); A3.x += __shfl_xor(A3.x, 32, 64);
    A3.y += __shfl_xor(A3.y, 16, 64); A3.y += __shfl_xor(A3.y, 32, 64);

    uint4 hv = *(const uint4*)(hb + ((size_t)n << 8) + coff);
    unsigned hvg = (g == 0) ? hv.x : (g == 1) ? hv.y : (g == 2) ? hv.z : hv.w;
    float sx, sy;
    if (g == 0)      { sx = A0.x; sy = A0.y; }
    else if (g == 1) { sx = A1.x; sy = A1.y; }
    else if (g == 2) { sx = A2.x; sy = A2.y; }
    else             { sx = A3.x; sy = A3.y; }

    float ax = (sx + bflo(hvg)) * dn;   // self row already pre-scaled
    float ay = (sy + bfhi(hvg)) * dn;
    float2 bv = ((const float2*)bias)[f0 * 4 + g];
    ax += bv.x;
    ay += bv.y;
    int fi = f0 * 8 + g * 2;
    if (MODE == 1) {
        unsigned idx = (unsigned)n * 128u + (unsigned)fi;
        ax = fmaxf(ax, 0.f) * dropout_scale(idx);
        ay = fmaxf(ay, 0.f) * dropout_scale(idx + 1u);
        ((unsigned*)outp)[(size_t)n * 64 + f0 * 4 + g] =
            (unsigned)f2bf(ax) | ((unsigned)f2bf(ay) << 16);
    } else {
        ((float2*)outp)[(size_t)n * 64 + f0 * 4 + g] = make_float2(ax, ay);
    }
}

// ---------------- launcher ---------------------------------------------------
extern "C" void kernel_launch(void* const* d_in, const int* in_sizes, int n_in,
                              void* d_out, int out_size, void* d_ws, size_t ws_size,
                              hipStream_t stream) {
    const float* X  = (const float*)d_in[0];
    const int*   ei = (const int*)d_in[1];
    const float* W1 = (const float*)d_in[2];
    const float* b1 = (const float*)d_in[3];
    const float* W2 = (const float*)d_in[4];
    const float* b2 = (const float*)d_in[5];
    float* out = (float*)d_out;

    const int N = in_sizes[0] / IN_DIM;  // 100000
    const int E = in_sizes[1] / 2;       // 1600000
    const int* src = ei;
    const int* dst = ei + E;
    const int total = N * HID;
    const size_t N4 = (size_t)N * 4;
    const size_t tot2 = (size_t)total * 2;
    const int NBKT = (N + BKT_SZ - 1) >> BKT_BITS;
    const int M = NBKT * NB_BLK;
    const int per = (E + NB_BLK - 1) / NB_BLK;
    const int snb = (M + 2047) / 2048;
    const int na = HID * IN_DIM, nb = HID * HID;

    char* ws = (char*)d_ws;
    size_t off = 0;
    unsigned short* hA = (unsigned short*)(ws + off); off += tot2 + HID * 2; // +zero row
    unsigned short* hB = (unsigned short*)(ws + off); off += tot2;
    float* dinv = (float*)(ws + off); off += N4;
    int* offs   = (int*)(ws + off); off += N4;
    int* counts = (int*)(ws + off); off += (size_t)M * 4;
    int* cbase  = (int*)(ws + off); off += (size_t)M * 4;
    int* bsum   = (int*)(ws + off); off += 4096;
    int* bbase  = (int*)(ws + off); off += (size_t)(MAXBKT + 1) * 4;
    unsigned* packed = (unsigned*)(ws + off); off += (size_t)E * 4;
    int* ssrc   = (int*)(ws + off); off += (size_t)E * 4;
    unsigned short* Wb1 = (unsigned short*)(ws + off); off += (size_t)na * 2;
    unsigned short* Wb2 = (unsigned short*)(ws + off);

    // fused setup: part_count histogram + W->bf16 + zero row
    const int cvt_blocks = (na + nb + HID + 255) / 256;
    setup<<<NB_BLK + cvt_blocks, 256, 0, stream>>>(dst, counts, E, NBKT, per,
                                                   W1, Wb1, na, W2, Wb2, nb,
                                                   hA + (size_t)N * HID);
    scan2_local<<<snb, 256, 0, stream>>>(counts, cbase, bsum, M);
    scan2_bsums<<<1, 256, 0, stream>>>(bsum, snb);
    scan2_add<<<(M + 255) / 256, 256, 0, stream>>>(cbase, bsum, bbase, M, NBKT, E);
    part_scatter<<<NB_BLK, 256, 0, stream>>>(src, dst, cbase, packed, E, NBKT, per);
    bucket_finalize<<<NBKT, 256, 0, stream>>>(packed, bbase, ssrc, offs, dinv, N);

    // layer 1: h1' = dinv * (X W1^T)
    gemm_mfma<256, 0><<<(N + 63) / 64, 256, 0, stream>>>(X, Wb1, dinv, hA, N);
    aggregate_csr<1><<<N, 64, 0, stream>>>((const unsigned*)hA, offs, ssrc,
                                           dinv, b1, hB, N, E);
    // layer 2: h2' = dinv * (h1drop W2^T)
    gemm_mfma<128, 1><<<(N + 63) / 64, 256, 0, stream>>>(hB, Wb2, dinv, hA, N);
    aggregate_csr<2><<<N, 64, 0, stream>>>((const unsigned*)hA, offs, ssrc,
                                           dinv, b2, out, N, E);
}

// Round 14
// 251.735 us; speedup vs baseline: 1.0363x; 1.0363x over previous
//
#include <hip/hip_runtime.h>
#include <stdint.h>

#define IN_DIM 256
#define HID 128
#define BKT_BITS 6
#define BKT_SZ 64
#define MAXBKT 2048
#define NB_BLK 256   // partitions for contention-free scatter

typedef __attribute__((ext_vector_type(8))) short short8v;   // 8 bf16 (4 VGPRs)
typedef __attribute__((ext_vector_type(4))) float f32x4;     // MFMA acc
typedef __attribute__((ext_vector_type(2))) float f32x2;     // pk_add pair

// ---------------- bf16 helpers ----------------------------------------------
__device__ __forceinline__ unsigned short f2bf(float f) {
    unsigned u = __float_as_uint(f);
    unsigned rnd = 0x7FFFu + ((u >> 16) & 1u);
    return (unsigned short)((u + rnd) >> 16);
}
__device__ __forceinline__ float bflo(unsigned v) { return __uint_as_float(v << 16); }
__device__ __forceinline__ float bfhi(unsigned v) { return __uint_as_float(v & 0xFFFF0000u); }

// packed dual-f32 accumulate: acc.x += lo(v), acc.y += hi(v)
__device__ __forceinline__ void pkacc(f32x2& acc, unsigned v) {
    f32x2 t;
    t.x = __uint_as_float(v << 16);
    t.y = __uint_as_float(v & 0xFFFF0000u);
    asm("v_pk_add_f32 %0, %0, %1" : "+v"(acc) : "v"(t));
}

// ---------------- threefry2x32 dropout (JAX partitionable path) -------------
__device__ __forceinline__ unsigned rotl32(unsigned x, int r) {
    return (x << r) | (x >> (32 - r));
}
__device__ __forceinline__ float dropout_scale(unsigned idx) {
    const unsigned ks0 = 0u, ks1 = 42u, ks2 = 0x1BD11BF0u;
    unsigned x0 = 0u + ks0;
    unsigned x1 = idx + ks1;
#define TF_ROUND(r) { x0 += x1; x1 = rotl32(x1, r); x1 ^= x0; }
    TF_ROUND(13) TF_ROUND(15) TF_ROUND(26) TF_ROUND(6)
    x0 += ks1; x1 += ks2 + 1u;
    TF_ROUND(17) TF_ROUND(29) TF_ROUND(16) TF_ROUND(24)
    x0 += ks2; x1 += ks0 + 2u;
    TF_ROUND(13) TF_ROUND(15) TF_ROUND(26) TF_ROUND(6)
    x0 += ks0; x1 += ks1 + 3u;
    TF_ROUND(17) TF_ROUND(29) TF_ROUND(16) TF_ROUND(24)
    x0 += ks1; x1 += ks2 + 4u;
    TF_ROUND(13) TF_ROUND(15) TF_ROUND(26) TF_ROUND(6)
    x0 += ks2; x1 += ks0 + 5u;
#undef TF_ROUND
    unsigned bits = x0 ^ x1;
    float u = __uint_as_float(0x3F800000u | (bits >> 9)) - 1.0f;
    return (u < 0.9f) ? (1.0f / 0.9f) : 0.0f;
}

// ---------------- partitioned bucket CSR build ------------------------------
__global__ __launch_bounds__(256) void part_count(const int* __restrict__ dst,
                                                  int* __restrict__ counts,
                                                  int E, int nbkt, int per) {
    __shared__ int lh[MAXBKT];
    for (int i = threadIdx.x; i < nbkt; i += 256) lh[i] = 0;
    __syncthreads();
    int blk = blockIdx.x;
    int beg = blk * per, end = min(E, beg + per);
    for (int i = beg + threadIdx.x; i < end; i += 256)
        atomicAdd(&lh[dst[i] >> BKT_BITS], 1);
    __syncthreads();
    for (int b = threadIdx.x; b < nbkt; b += 256)
        counts[b * NB_BLK + blk] = lh[b];
}

__global__ __launch_bounds__(256) void scan2_local(const int* __restrict__ in,
                                                   int* __restrict__ out,
                                                   int* __restrict__ bsum, int M) {
    __shared__ int lds[256];
    int t = threadIdx.x;
    int base = blockIdx.x * 2048 + t * 8;
    int x[8], v[8];
    if (base + 7 < M) {
        int4 a = *(const int4*)(in + base);
        int4 b = *(const int4*)(in + base + 4);
        x[0] = a.x; x[1] = a.y; x[2] = a.z; x[3] = a.w;
        x[4] = b.x; x[5] = b.y; x[6] = b.z; x[7] = b.w;
    } else {
        for (int j = 0; j < 8; ++j) x[j] = (base + j < M) ? in[base + j] : 0;
    }
    int s = 0;
    for (int j = 0; j < 8; ++j) { v[j] = s; s += x[j]; }
    lds[t] = s;
    __syncthreads();
    for (int d = 1; d < 256; d <<= 1) {
        int val = lds[t];
        int add = (t >= d) ? lds[t - d] : 0;
        __syncthreads();
        lds[t] = val + add;
        __syncthreads();
    }
    int excl = lds[t] - s;
    for (int j = 0; j < 8; ++j)
        if (base + j < M) out[base + j] = excl + v[j];
    if (t == 255) bsum[blockIdx.x] = lds[255];
}
__global__ __launch_bounds__(256) void scan2_bsums(int* __restrict__ bsum, int nb) {
    __shared__ int lds[256];
    int t = threadIdx.x;
    int orig = (t < nb) ? bsum[t] : 0;
    lds[t] = orig;
    __syncthreads();
    for (int d = 1; d < 256; d <<= 1) {
        int val = lds[t];
        int add = (t >= d) ? lds[t - d] : 0;
        __syncthreads();
        lds[t] = val + add;
        __syncthreads();
    }
    if (t < nb) bsum[t] = lds[t] - orig;
}
// adds scanned block sums AND extracts bucket bases (fused extract_bbase)
__global__ void scan2_add(int* __restrict__ out, const int* __restrict__ bsum,
                          int* __restrict__ bbase, int M, int nbkt, int E) {
    int i = blockIdx.x * blockDim.x + threadIdx.x;
    if (i < M) {
        int v = out[i] + bsum[i >> 11];
        out[i] = v;
        if ((i & (NB_BLK - 1)) == 0) bbase[i / NB_BLK] = v;
    }
    if (i == 0) bbase[nbkt] = E;
}

__global__ __launch_bounds__(256) void part_scatter(const int* __restrict__ src,
                                                    const int* __restrict__ dst,
                                                    const int* __restrict__ cbase,
                                                    unsigned* __restrict__ packed,
                                                    int E, int nbkt, int per) {
    __shared__ int cur[MAXBKT];
    int blk = blockIdx.x;
    for (int b = threadIdx.x; b < nbkt; b += 256)
        cur[b] = cbase[b * NB_BLK + blk];
    __syncthreads();
    int beg = blk * per, end = min(E, beg + per);
    for (int i = beg + threadIdx.x; i < end; i += 256) {
        int d = dst[i];
        int pos = atomicAdd(&cur[d >> BKT_BITS], 1);
        packed[pos] = ((unsigned)src[i] << BKT_BITS) | (unsigned)(d & (BKT_SZ - 1));
    }
}

// ssrc stores BYTE offsets (src << 8) for the 256-byte h rows.
__global__ __launch_bounds__(256) void bucket_finalize(const unsigned* __restrict__ packed,
                                                       const int* __restrict__ bbase,
                                                       int* __restrict__ ssrc,
                                                       int* __restrict__ offs,
                                                       float* __restrict__ dinv, int N) {
    __shared__ int hist[BKT_SZ];
    __shared__ int cur[BKT_SZ];
    int b = blockIdx.x;
    int t = threadIdx.x;
    int beg = bbase[b], end = bbase[b + 1];
    if (t < BKT_SZ) hist[t] = 0;
    __syncthreads();
    for (int i = beg + t; i < end; i += 256)
        atomicAdd(&hist[packed[i] & (BKT_SZ - 1)], 1);
    __syncthreads();
    if (t < BKT_SZ) cur[t] = hist[t];
    __syncthreads();
    for (int d = 1; d < BKT_SZ; d <<= 1) {
        int val = 0;
        if (t < BKT_SZ) { val = cur[t]; if (t >= d) val += cur[t - d]; }
        __syncthreads();
        if (t < BKT_SZ) cur[t] = val;
        __syncthreads();
    }
    if (t < BKT_SZ) {
        int node = b * BKT_SZ + t;
        int excl = cur[t] - hist[t];
        if (node < N) {
            offs[node] = beg + excl;
            dinv[node] = rsqrtf((float)(hist[t] + 1));
        }
        cur[t] = excl;
    }
    __syncthreads();
    for (int i = beg + t; i < end; i += 256) {
        unsigned p = packed[i];
        int dl = (int)(p & (BKT_SZ - 1));
        int pos = atomicAdd(&cur[dl], 1);
        ssrc[beg + pos] = (int)((p >> BKT_BITS) << 8);   // byte offset
    }
}

// ---------------- weight fp32 -> bf16 (both weights, one launch) ------------
__global__ void cvt_w2(const float* __restrict__ Wa, unsigned short* __restrict__ Oa, int na,
                       const float* __restrict__ Wb, unsigned short* __restrict__ Ob, int nb) {
    int i = blockIdx.x * blockDim.x + threadIdx.x;
    if (i < na) Oa[i] = f2bf(Wa[i]);
    else if (i - na < nb) Ob[i - na] = f2bf(Wb[i - na]);
}

// ---------------- bf16 MFMA GEMM: C[Mx128] = diag(scale) * A[MxK] @ W^T -----
template <int K, int A_BF16>
__global__ __launch_bounds__(256) void gemm_mfma(const void* __restrict__ Ap,
                                                 const unsigned short* __restrict__ Wb,
                                                 const float* __restrict__ scale,
                                                 unsigned short* __restrict__ C,
                                                 int M) {
    constexpr int NKB = K / 32;
    constexpr int APAD = K + 8;
    __shared__ unsigned short Alds[64 * APAD];
    const int t = threadIdx.x;
    const int bm = blockIdx.x * 64;
    const int w = t >> 6, l = t & 63;
    const int lr = l & 15, lk = l >> 4;

    short8v bfrag[2][NKB];
#pragma unroll
    for (int cbi = 0; cbi < 2; ++cbi) {
        int col = (w * 2 + cbi) * 16 + lr;
#pragma unroll
        for (int kb = 0; kb < NKB; ++kb)
            bfrag[cbi][kb] = *(const short8v*)(Wb + (size_t)col * K + kb * 32 + lk * 8);
    }

    if constexpr (A_BF16) {
        constexpr int STEPS = 64 * K / (256 * 8);
        const unsigned short* Abase = (const unsigned short*)Ap;
#pragma unroll
        for (int i = 0; i < STEPS; ++i) {
            int flat = (i * 256 + t) * 8;
            int row = flat / K;
            int o = flat % K;
            short8v v = {};
            if (bm + row < M)
                v = *(const short8v*)(Abase + (size_t)(bm + row) * K + o);
            *(short8v*)(&Alds[row * APAD + o]) = v;
        }
    } else {
        constexpr int STEPS = 64 * K / (256 * 8);
        const float* Abase = (const float*)Ap;
#pragma unroll
        for (int i = 0; i < STEPS; ++i) {
            int flat = (i * 256 + t) * 8;
            int row = flat / K;
            int o = flat % K;
            short8v u = {};
            if (bm + row < M) {
                const float* p = Abase + (size_t)(bm + row) * K + o;
                float4 f0 = *(const float4*)(p);
                float4 f1 = *(const float4*)(p + 4);
                u[0] = (short)f2bf(f0.x); u[1] = (short)f2bf(f0.y);
                u[2] = (short)f2bf(f0.z); u[3] = (short)f2bf(f0.w);
                u[4] = (short)f2bf(f1.x); u[5] = (short)f2bf(f1.y);
                u[6] = (short)f2bf(f1.z); u[7] = (short)f2bf(f1.w);
            }
            *(short8v*)(&Alds[row * APAD + o]) = u;
        }
    }
    __syncthreads();

#pragma unroll
    for (int m = 0; m < 4; ++m) {
        short8v afr[NKB];
#pragma unroll
        for (int kb = 0; kb < NKB; ++kb)
            afr[kb] = *(const short8v*)(&Alds[(m * 16 + lr) * APAD + kb * 32 + lk * 8]);
        f32x4 acc[2] = {};
#pragma unroll
        for (int kb = 0; kb < NKB; ++kb) {
            acc[0] = __builtin_amdgcn_mfma_f32_16x16x32_bf16(afr[kb], bfrag[0][kb], acc[0], 0, 0, 0);
            acc[1] = __builtin_amdgcn_mfma_f32_16x16x32_bf16(afr[kb], bfrag[1][kb], acc[1], 0, 0, 0);
        }
        int r0 = bm + m * 16 + lk * 4;
        float scv[4];
#pragma unroll
        for (int j = 0; j < 4; ++j)
            scv[j] = (r0 + j < M) ? scale[r0 + j] : 0.f;
#pragma unroll
        for (int cbi = 0; cbi < 2; ++cbi) {
            int col = (w * 2 + cbi) * 16 + lr;
#pragma unroll
            for (int j = 0; j < 4; ++j) {
                if (r0 + j < M)
                    C[(size_t)(r0 + j) * 128 + col] = f2bf(acc[cbi][j] * scv[j]);
            }
        }
    }
}

// ---------------- CSR gather aggregation: 1 node per 64-thr block -----------
// h rows pre-scaled (h' = dinv*h); row N all-zero; ssrc holds BYTE offsets.
// 16 lanes per edge; 16 edges per iteration; offset loads software-pipelined.
// MODE 1: out(bf16) = dropout(relu(dn*sum + b));  MODE 2: out(fp32) = dn*sum + b
template <int MODE>
__global__ __launch_bounds__(64) void aggregate_csr(const unsigned* __restrict__ h,
                                                    const int* __restrict__ soff,
                                                    const int* __restrict__ ssrc,
                                                    const float* __restrict__ dinv,
                                                    const float* __restrict__ bias,
                                                    void* __restrict__ outp,
                                                    int N, int E) {
    int n = blockIdx.x;
    const int lane = threadIdx.x;
    const int g = lane >> 4;      // edge group 0..3
    const int f0 = lane & 15;     // 16B chunk within the 256B row
    int start = soff[n];
    int end = (n + 1 < N) ? soff[n + 1] : E;
    float dn = dinv[n];
    const char* __restrict__ hb = (const char*)h;
    const int zoff = N << 8;      // zero row byte offset
    const int coff = f0 * 16;     // chunk byte offset within row

    f32x2 A0 = {0.f, 0.f}, A1 = {0.f, 0.f}, A2 = {0.f, 0.f}, A3 = {0.f, 0.f};

    int i = start;
    int o0 = zoff, o1 = zoff, o2 = zoff, o3 = zoff;
    {
        int i0 = i + g, i1 = i0 + 4, i2 = i0 + 8, i3 = i0 + 12;
        if (i0 < end) o0 = ssrc[i0];
        if (i1 < end) o1 = ssrc[i1];
        if (i2 < end) o2 = ssrc[i2];
        if (i3 < end) o3 = ssrc[i3];
    }
    for (; i < end; i += 16) {
        uint4 v0 = *(const uint4*)(hb + (size_t)o0 + coff);
        uint4 v1 = *(const uint4*)(hb + (size_t)o1 + coff);
        uint4 v2 = *(const uint4*)(hb + (size_t)o2 + coff);
        uint4 v3 = *(const uint4*)(hb + (size_t)o3 + coff);
        int ni = i + 16;
        int i0 = ni + g, i1 = i0 + 4, i2 = i0 + 8, i3 = i0 + 12;
        o0 = (i0 < end) ? ssrc[i0] : zoff;
        o1 = (i1 < end) ? ssrc[i1] : zoff;
        o2 = (i2 < end) ? ssrc[i2] : zoff;
        o3 = (i3 < end) ? ssrc[i3] : zoff;
        pkacc(A0, v0.x); pkacc(A1, v0.y); pkacc(A2, v0.z); pkacc(A3, v0.w);
        pkacc(A0, v1.x); pkacc(A1, v1.y); pkacc(A2, v1.z); pkacc(A3, v1.w);
        pkacc(A0, v2.x); pkacc(A1, v2.y); pkacc(A2, v2.z); pkacc(A3, v2.w);
        pkacc(A0, v3.x); pkacc(A1, v3.y); pkacc(A2, v3.z); pkacc(A3, v3.w);
    }

    A0.x += __shfl_xor(A0.x, 16, 64); A0.x += __shfl_xor(A0.x, 32, 64);
    A0.y += __shfl_xor(A0.y, 16, 64); A0.y += __shfl_xor(A0.y, 32, 64);
    A1.x += __shfl_xor(A1.x, 16, 64); A1.x += __shfl_xor(A1.x, 32, 64);
    A1.y += __shfl_xor(A1.y, 16, 64); A1.y += __shfl_xor(A1.y, 32, 64);
    A2.x += __shfl_xor(A2.x, 16, 64); A2.x += __shfl_xor(A2.x, 32, 64);
    A2.y += __shfl_xor(A2.y, 16, 64); A2.y += __shfl_xor(A2.y, 32, 64);
    A3.x += __shfl_xor(A3.x, 16, 64); A3.x += __shfl_xor(A3.x, 32, 64);
    A3.y += __shfl_xor(A3.y, 16, 64); A3.y += __shfl_xor(A3.y, 32, 64);

    uint4 hv = *(const uint4*)(hb + ((size_t)n << 8) + coff);
    unsigned hvg = (g == 0) ? hv.x : (g == 1) ? hv.y : (g == 2) ? hv.z : hv.w;
    float sx, sy;
    if (g == 0)      { sx = A0.x; sy = A0.y; }
    else if (g == 1) { sx = A1.x; sy = A1.y; }
    else if (g == 2) { sx = A2.x; sy = A2.y; }
    else             { sx = A3.x; sy = A3.y; }

    float ax = (sx + bflo(hvg)) * dn;   // self row already pre-scaled
    float ay = (sy + bfhi(hvg)) * dn;
    float2 bv = ((const float2*)bias)[f0 * 4 + g];
    ax += bv.x;
    ay += bv.y;
    int fi = f0 * 8 + g * 2;
    if (MODE == 1) {
        unsigned idx = (unsigned)n * 128u + (unsigned)fi;
        ax = fmaxf(ax, 0.f) * dropout_scale(idx);
        ay = fmaxf(ay, 0.f) * dropout_scale(idx + 1u);
        ((unsigned*)outp)[(size_t)n * 64 + f0 * 4 + g] =
            (unsigned)f2bf(ax) | ((unsigned)f2bf(ay) << 16);
    } else {
        ((float2*)outp)[(size_t)n * 64 + f0 * 4 + g] = make_float2(ax, ay);
    }
}

// ---------------- launcher ---------------------------------------------------
extern "C" void kernel_launch(void* const* d_in, const int* in_sizes, int n_in,
                              void* d_out, int out_size, void* d_ws, size_t ws_size,
                              hipStream_t stream) {
    const float* X  = (const float*)d_in[0];
    const int*   ei = (const int*)d_in[1];
    const float* W1 = (const float*)d_in[2];
    const float* b1 = (const float*)d_in[3];
    const float* W2 = (const float*)d_in[4];
    const float* b2 = (const float*)d_in[5];
    float* out = (float*)d_out;

    const int N = in_sizes[0] / IN_DIM;  // 100000
    const int E = in_sizes[1] / 2;       // 1600000
    const int* src = ei;
    const int* dst = ei + E;
    const int total = N * HID;
    const size_t N4 = (size_t)N * 4;
    const size_t tot2 = (size_t)total * 2;
    const int NBKT = (N + BKT_SZ - 1) >> BKT_BITS;
    const int M = NBKT * NB_BLK;
    const int per = (E + NB_BLK - 1) / NB_BLK;
    const int snb = (M + 2047) / 2048;

    char* ws = (char*)d_ws;
    size_t off = 0;
    unsigned short* hA = (unsigned short*)(ws + off); off += tot2 + HID * 2; // +zero row
    unsigned short* hB = (unsigned short*)(ws + off); off += tot2;
    float* dinv = (float*)(ws + off); off += N4;
    int* offs   = (int*)(ws + off); off += N4;
    int* counts = (int*)(ws + off); off += (size_t)M * 4;
    int* cbase  = (int*)(ws + off); off += (size_t)M * 4;
    int* bsum   = (int*)(ws + off); off += 4096;
    int* bbase  = (int*)(ws + off); off += (size_t)(MAXBKT + 1) * 4;
    unsigned* packed = (unsigned*)(ws + off); off += (size_t)E * 4;
    int* ssrc   = (int*)(ws + off); off += (size_t)E * 4;
    unsigned short* Wb1 = (unsigned short*)(ws + off); off += (size_t)HID * IN_DIM * 2;
    unsigned short* Wb2 = (unsigned short*)(ws + off);

    // zero row at hA[N] (gather-tail padding); persists across both layers
    hipMemsetAsync(hA + (size_t)N * HID, 0, HID * 2, stream);

    // CSR build (partitioned, contention-free) + weight conversion
    cvt_w2<<<(HID * IN_DIM + HID * HID + 255) / 256, 256, 0, stream>>>(
        W1, Wb1, HID * IN_DIM, W2, Wb2, HID * HID);
    part_count<<<NB_BLK, 256, 0, stream>>>(dst, counts, E, NBKT, per);
    scan2_local<<<snb, 256, 0, stream>>>(counts, cbase, bsum, M);
    scan2_bsums<<<1, 256, 0, stream>>>(bsum, snb);
    scan2_add<<<(M + 255) / 256, 256, 0, stream>>>(cbase, bsum, bbase, M, NBKT, E);
    part_scatter<<<NB_BLK, 256, 0, stream>>>(src, dst, cbase, packed, E, NBKT, per);
    bucket_finalize<<<NBKT, 256, 0, stream>>>(packed, bbase, ssrc, offs, dinv, N);

    // layer 1: h1' = dinv * (X W1^T)
    gemm_mfma<256, 0><<<(N + 63) / 64, 256, 0, stream>>>(X, Wb1, dinv, hA, N);
    aggregate_csr<1><<<N, 64, 0, stream>>>((const unsigned*)hA, offs, ssrc,
                                           dinv, b1, hB, N, E);
    // layer 2: h2' = dinv * (h1drop W2^T)
    gemm_mfma<128, 1><<<(N + 63) / 64, 256, 0, stream>>>(hB, Wb2, dinv, hA, N);
    aggregate_csr<2><<<N, 64, 0, stream>>>((const unsigned*)hA, offs, ssrc,
                                           dinv, b2, out, N, E);
}